// Round 1
// baseline (127287.622 us; speedup 1.0000x reference)
//
#include <hip/hip_runtime.h>
#include <hip/hip_bf16.h>

#define T_STEPS 16384
#define COMD 128
#define INPD 512
#define HIDD 2048
#define OUTD 512
#define DIN 640
#define SCALE_F 35.0f
#define NTEAM 32
#define HS 64

using u16 = unsigned short;
using u32 = unsigned int;

__device__ __forceinline__ float lrelu(float x){ return x >= 0.f ? x : 0.01f*x; }
__device__ __forceinline__ float bf2f(u16 u){ return __uint_as_float(((u32)u)<<16); }
__device__ __forceinline__ u16 f2bf(float f){ u32 x = __float_as_uint(f); return (u16)((x + 0x7fffu + ((x>>16)&1u)) >> 16); }

// ---------------- prep: base1/base2 = W1[:, :512] @ i + b ----------------
__global__ void __launch_bounds__(256) prep_base_kernel(
    const float* __restrict__ I1, const float* __restrict__ I2,
    const float* __restrict__ W11, const float* __restrict__ b11,
    const float* __restrict__ W21, const float* __restrict__ b21,
    float* __restrict__ base)
{
  int row = blockIdx.x*4 + (threadIdx.x>>6);   // 0..4095
  int lane = threadIdx.x & 63;
  int agent = row >> 11;
  int h = row & 2047;
  const float* W  = agent ? W21 : W11;
  const float* in = agent ? I2  : I1;   // row 0 only
  const float* bv = agent ? b21 : b11;
  float acc = 0.f;
  #pragma unroll
  for (int k = 0; k < 8; ++k)
    acc += W[(size_t)h*DIN + k*64 + lane] * in[k*64 + lane];
  #pragma unroll
  for (int off = 32; off; off >>= 1) acc += __shfl_xor(acc, off);
  if (lane == 0) base[agent*HIDD + h] = acc + bv[h];
}

// ---------------- prep: bf16 out-head weights (rows 0..511) ----------------
__global__ void __launch_bounds__(256) cvt_kernel(
    const float* __restrict__ W12, const float* __restrict__ W22,
    u16* __restrict__ o1, u16* __restrict__ o2)
{
  size_t i = ((size_t)blockIdx.x*256 + threadIdx.x)*4;   // < 512*2048
  float4 a = *reinterpret_cast<const float4*>(W12 + i);
  float4 b = *reinterpret_cast<const float4*>(W22 + i);
  ushort4 ua = { f2bf(a.x), f2bf(a.y), f2bf(a.z), f2bf(a.w) };
  ushort4 ub = { f2bf(b.x), f2bf(b.y), f2bf(b.z), f2bf(b.w) };
  *reinterpret_cast<ushort4*>(o1 + i) = ua;
  *reinterpret_cast<ushort4*>(o2 + i) = ub;
}

// ---------------- redundant 128-softmax within each team WG ----------------
__device__ __forceinline__ void softmax128(const int tid, float* s_z, float* s_red, float* s_com)
{
  if (tid < COMD) {
    float m = s_z[tid];
    #pragma unroll
    for (int off = 32; off; off >>= 1) m = fmaxf(m, __shfl_xor(m, off));
    if ((tid & 63) == 0) s_red[tid>>6] = m;
  }
  __syncthreads();
  float M = fmaxf(s_red[0], s_red[1]);
  float e = 0.f;
  if (tid < COMD) e = __expf(s_z[tid] - M);
  float ssum = e;
  #pragma unroll
  for (int off = 32; off; off >>= 1) ssum += __shfl_xor(ssum, off);
  if (tid < COMD && (tid & 63) == 0) s_red[4 + (tid>>6)] = ssum;
  __syncthreads();
  if (tid < COMD) s_com[tid] = e / (s_red[4] + s_red[5]);
  __syncthreads();
}

// ---------------- the sequential recurrence: 32 WGs, hidden-sliced ----------------
__global__ void __launch_bounds__(512, 1) team_kernel(
    const float* __restrict__ W11, const float* __restrict__ W21,
    const float* __restrict__ W12, const float* __restrict__ W22,
    const float* __restrict__ b12, const float* __restrict__ b22,
    const float* __restrict__ base,
    float* __restrict__ P1, float* __restrict__ P2, u32* __restrict__ cnts,
    void* __restrict__ hist1, void* __restrict__ hist2, int hf32)
{
  __shared__ float sWa1[HS*129];   // A1W1_w[:, 512:]  slice, [h][c] pad129
  __shared__ float sWa2[HS*129];   // A2W1_w[:, 512:]
  __shared__ float sU1[COMD*65];   // A1W2_w[512:, :]  slice, [o][h] pad65
  __shared__ float sU2[COMD*65];   // A2W2_w[512:, :]
  __shared__ float s_b1[HS], s_b2[HS], s_w[HS], s_v[HS], s_h1a[HS], s_h2[HS];
  __shared__ float s_bc1[COMD], s_bc2[COMD], s_com[COMD], s_z[COMD];
  __shared__ float s_lp[512];
  __shared__ float s_red[8];

  const int g = blockIdx.x;
  const int tid = threadIdx.x;
  const int h0 = g*HS;

  for (int idx = tid; idx < HS*COMD; idx += 512) {
    int h = idx >> 7, c = idx & 127;
    sWa1[h*129+c] = W11[(size_t)(h0+h)*DIN + INPD + c];
    sWa2[h*129+c] = W21[(size_t)(h0+h)*DIN + INPD + c];
  }
  for (int idx = tid; idx < COMD*HS; idx += 512) {
    int o = idx >> 6, h = idx & 63;
    sU1[o*65+h] = W12[(size_t)(OUTD+o)*HIDD + h0 + h];
    sU2[o*65+h] = W22[(size_t)(OUTD+o)*HIDD + h0 + h];
  }
  if (tid < COMD) { s_bc1[tid] = b12[OUTD+tid]; s_bc2[tid] = b22[OUTD+tid]; }
  if (tid < HS)   { s_b1[tid] = base[h0+tid]; s_b2[tid] = base[HIDD+h0+tid]; s_w[tid]=0.f; s_v[tid]=0.f; }
  __syncthreads();

  float* h1f = (float*)hist1; u16* h1u = (u16*)hist1;
  float* h2f = (float*)hist2; u16* h2u = (u16*)hist2;

  for (int t = 0; t < T_STEPS; ++t) {
    const float invd = 1.f/(float)(t+1);

    // h1a = lrelu(base1 + (W@sum_c2)/denom)
    if (tid < HS) s_h1a[tid] = lrelu(s_b1[tid] + s_w[tid]*invd);
    __syncthreads();

    // partial com1 logits over our hidden slice
    {
      int r = tid >> 7, o = tid & 127;
      const float* Up = &sU1[o*65 + r*16];
      const float* hp = &s_h1a[r*16];
      float acc = 0.f;
      #pragma unroll
      for (int j = 0; j < 16; ++j) acc += Up[j]*hp[j];
      s_lp[tid] = acc;
    }
    __syncthreads();
    if (tid < COMD) {
      float pl = s_lp[tid] + s_lp[COMD+tid] + s_lp[2*COMD+tid] + s_lp[3*COMD+tid];
      __hip_atomic_store(&P1[g*COMD + tid], pl, __ATOMIC_RELAXED, __HIP_MEMORY_SCOPE_AGENT);
    }
    __syncthreads();
    if (tid == 0) {
      __hip_atomic_fetch_add(&cnts[0], 1u, __ATOMIC_RELEASE, __HIP_MEMORY_SCOPE_AGENT);
      while (__hip_atomic_load(&cnts[0], __ATOMIC_ACQUIRE, __HIP_MEMORY_SCOPE_AGENT) < (u32)(NTEAM*(t+1))) {}
    }
    __syncthreads();
    // gather all partials, reduce + softmax redundantly
    {
      int o = tid & 127, grp = tid >> 7;
      float s = 0.f;
      #pragma unroll
      for (int j = 0; j < 8; ++j)
        s += __hip_atomic_load(&P1[(grp*8+j)*COMD + o], __ATOMIC_RELAXED, __HIP_MEMORY_SCOPE_AGENT);
      s_lp[tid] = s;
    }
    __syncthreads();
    if (tid < COMD) {
      float d = s_lp[tid]+s_lp[COMD+tid]+s_lp[2*COMD+tid]+s_lp[3*COMD+tid] + s_bc1[tid];
      s_z[tid] = SCALE_F * lrelu(d);
    }
    __syncthreads();
    softmax128(tid, s_z, s_red, s_com);   // s_com = com1

    // v += A2W1c @ com1
    {
      int w = tid >> 6, lane = tid & 63;
      const float* Wp = &sWa2[lane*129 + w*16];
      const float* cp = &s_com[w*16];
      float acc = 0.f;
      #pragma unroll
      for (int j = 0; j < 16; ++j) acc += Wp[j]*cp[j];
      s_lp[tid] = acc;
    }
    __syncthreads();
    if (tid < HS) {
      float s = s_v[tid];
      #pragma unroll
      for (int w = 0; w < 8; ++w) s += s_lp[w*64 + tid];
      s_v[tid] = s;
      float x = lrelu(s_b2[tid] + s*invd);
      s_h2[tid] = x;
      if (hf32) h2f[(size_t)t*HIDD + h0 + tid] = x; else h2u[(size_t)t*HIDD + h0 + tid] = f2bf(x);
    }
    __syncthreads();

    // partial com2 logits
    {
      int r = tid >> 7, o = tid & 127;
      const float* Up = &sU2[o*65 + r*16];
      const float* hp = &s_h2[r*16];
      float acc = 0.f;
      #pragma unroll
      for (int j = 0; j < 16; ++j) acc += Up[j]*hp[j];
      s_lp[tid] = acc;
    }
    __syncthreads();
    if (tid < COMD) {
      float pl = s_lp[tid] + s_lp[COMD+tid] + s_lp[2*COMD+tid] + s_lp[3*COMD+tid];
      __hip_atomic_store(&P2[g*COMD + tid], pl, __ATOMIC_RELAXED, __HIP_MEMORY_SCOPE_AGENT);
    }
    __syncthreads();
    if (tid == 0) {
      __hip_atomic_fetch_add(&cnts[1], 1u, __ATOMIC_RELEASE, __HIP_MEMORY_SCOPE_AGENT);
      while (__hip_atomic_load(&cnts[1], __ATOMIC_ACQUIRE, __HIP_MEMORY_SCOPE_AGENT) < (u32)(NTEAM*(t+1))) {}
    }
    __syncthreads();
    {
      int o = tid & 127, grp = tid >> 7;
      float s = 0.f;
      #pragma unroll
      for (int j = 0; j < 8; ++j)
        s += __hip_atomic_load(&P2[(grp*8+j)*COMD + o], __ATOMIC_RELAXED, __HIP_MEMORY_SCOPE_AGENT);
      s_lp[tid] = s;
    }
    __syncthreads();
    if (tid < COMD) {
      float d = s_lp[tid]+s_lp[COMD+tid]+s_lp[2*COMD+tid]+s_lp[3*COMD+tid] + s_bc2[tid];
      s_z[tid] = SCALE_F * lrelu(d);
    }
    __syncthreads();
    softmax128(tid, s_z, s_red, s_com);   // s_com = com2

    // w += A1W1c @ com2 ; h1b = lrelu(base1 + w/denom)
    {
      int w = tid >> 6, lane = tid & 63;
      const float* Wp = &sWa1[lane*129 + w*16];
      const float* cp = &s_com[w*16];
      float acc = 0.f;
      #pragma unroll
      for (int j = 0; j < 16; ++j) acc += Wp[j]*cp[j];
      s_lp[tid] = acc;
    }
    __syncthreads();
    if (tid < HS) {
      float s = s_w[tid];
      #pragma unroll
      for (int w = 0; w < 8; ++w) s += s_lp[w*64 + tid];
      s_w[tid] = s;
      float x = lrelu(s_b1[tid] + s*invd);
      if (hf32) h1f[(size_t)t*HIDD + h0 + tid] = x; else h1u[(size_t)t*HIDD + h0 + tid] = f2bf(x);
    }
    __syncthreads();
  }
}

// ---------------- dense out-heads from hidden history (t-blocked x8) ----------------
__global__ void __launch_bounds__(256) out_kernel(
    const void* __restrict__ hist1, const void* __restrict__ hist2,
    const u16* __restrict__ Wb1, const u16* __restrict__ Wb2,
    const float* __restrict__ b12, const float* __restrict__ b22,
    float* __restrict__ out, int hf32)
{
  __shared__ float hl[8][2048];
  const int head = blockIdx.x & 1;
  const int t0 = (blockIdx.x >> 1) * 8;
  const int tid = threadIdx.x;
  const void* hist = head ? hist2 : hist1;
  const u16* W = head ? Wb2 : Wb1;
  const float* bias = head ? b22 : b12;
  float* op = out + (size_t)head * T_STEPS * OUTD;

  if (hf32) {
    const float* hf = (const float*)hist;
    for (int idx = tid; idx < 8*2048; idx += 256)
      hl[idx>>11][idx&2047] = hf[(size_t)t0*HIDD + idx];
  } else {
    const u16* hu = (const u16*)hist;
    for (int idx = tid; idx < 8*2048; idx += 256)
      hl[idx>>11][idx&2047] = bf2f(hu[(size_t)t0*HIDD + idx]);
  }
  __syncthreads();

  const int wave = tid >> 6, lane = tid & 63;
  for (int row = wave; row < OUTD; row += 4) {
    const u16* wr = W + (size_t)row*HIDD;
    float acc[8] = {0,0,0,0,0,0,0,0};
    #pragma unroll
    for (int k = 0; k < 8; ++k) {
      const int e = k*256 + lane*4;
      uint2 pw = *reinterpret_cast<const uint2*>(wr + e);
      float w0 = bf2f((u16)(pw.x & 0xffffu));
      float w1 = bf2f((u16)(pw.x >> 16));
      float w2 = bf2f((u16)(pw.y & 0xffffu));
      float w3 = bf2f((u16)(pw.y >> 16));
      #pragma unroll
      for (int tt = 0; tt < 8; ++tt) {
        const float4 hv = *reinterpret_cast<const float4*>(&hl[tt][e]);
        acc[tt] += w0*hv.x + w1*hv.y + w2*hv.z + w3*hv.w;
      }
    }
    #pragma unroll
    for (int tt = 0; tt < 8; ++tt) {
      float a = acc[tt];
      #pragma unroll
      for (int off = 32; off; off >>= 1) a += __shfl_xor(a, off);
      acc[tt] = a;
    }
    if (lane == 0) {
      const float b = bias[row];
      #pragma unroll
      for (int tt = 0; tt < 8; ++tt)
        op[(size_t)(t0+tt)*OUTD + row] = lrelu(acc[tt] + b);
    }
  }
}

extern "C" void kernel_launch(void* const* d_in, const int* in_sizes, int n_in,
                              void* d_out, int out_size, void* d_ws, size_t ws_size,
                              hipStream_t stream)
{
  const float* I1  = (const float*)d_in[0];
  const float* I2  = (const float*)d_in[1];
  const float* W11 = (const float*)d_in[2];
  const float* b11 = (const float*)d_in[3];
  const float* W12 = (const float*)d_in[4];
  const float* b12 = (const float*)d_in[5];
  const float* W21 = (const float*)d_in[6];
  const float* b21 = (const float*)d_in[7];
  const float* W22 = (const float*)d_in[8];
  const float* b22 = (const float*)d_in[9];

  char* ws = (char*)d_ws;
  float* base = (float*)ws;                 // 2*2048 f32
  float* P1 = (float*)(ws + 16384);
  float* P2 = (float*)(ws + 32768);
  u32* cnts = (u32*)(ws + 49152);
  char* hist1 = ws + 65536;
  const size_t histF = (size_t)T_STEPS*HIDD*4;
  const size_t histU = (size_t)T_STEPS*HIDD*2;
  const size_t wbB   = (size_t)OUTD*HIDD*2;
  const size_t needF = 65536 + 2*histF + 2*wbB;
  int hf32 = (ws_size >= needF) ? 1 : 0;
  const size_t hb = hf32 ? histF : histU;
  char* hist2 = hist1 + hb;
  u16* Wb1 = (u16*)(hist2 + hb);
  u16* Wb2 = Wb1 + (size_t)OUTD*HIDD;

  hipMemsetAsync(cnts, 0, 256, stream);
  prep_base_kernel<<<1024, 256, 0, stream>>>(I1, I2, W11, b11, W21, b21, base);
  cvt_kernel<<<1024, 256, 0, stream>>>(W12, W22, Wb1, Wb2);

  void* h1v = (void*)hist1; void* h2v = (void*)hist2;
  void* kargs[] = { (void*)&W11, (void*)&W21, (void*)&W12, (void*)&W22,
                    (void*)&b12, (void*)&b22, (void*)&base,
                    (void*)&P1, (void*)&P2, (void*)&cnts,
                    (void*)&h1v, (void*)&h2v, (void*)&hf32 };
  hipLaunchCooperativeKernel((const void*)team_kernel, dim3(NTEAM), dim3(512),
                             kargs, 0, stream);

  out_kernel<<<(T_STEPS/8)*2, 256, 0, stream>>>(h1v, h2v, Wb1, Wb2, b12, b22,
                                                (float*)d_out, hf32);
}

// Round 3
// 121689.929 us; speedup vs baseline: 1.0460x; 1.0460x over previous
//
#include <hip/hip_runtime.h>
#include <hip/hip_bf16.h>

#define T_STEPS 16384
#define COMD 128
#define INPD 512
#define HIDD 2048
#define OUTD 512
#define DIN 640
#define SCALE_F 35.0f
#define NA 16      // WGs per agent
#define HSA 128    // hidden rows per WG

using u16 = unsigned short;
using u32 = unsigned int;

__device__ __forceinline__ float lrelu(float x){ return x >= 0.f ? x : 0.01f*x; }
__device__ __forceinline__ float bf2f(u16 u){ return __uint_as_float(((u32)u)<<16); }
__device__ __forceinline__ u16 f2bf(float f){ u32 x = __float_as_uint(f); return (u16)((x + 0x7fffu + ((x>>16)&1u)) >> 16); }

// ---------------- prep: base1/base2 = W1[:, :512] @ i + b ----------------
__global__ void __launch_bounds__(256) prep_base_kernel(
    const float* __restrict__ I1, const float* __restrict__ I2,
    const float* __restrict__ W11, const float* __restrict__ b11,
    const float* __restrict__ W21, const float* __restrict__ b21,
    float* __restrict__ base)
{
  int row = blockIdx.x*4 + (threadIdx.x>>6);   // 0..4095
  int lane = threadIdx.x & 63;
  int agent = row >> 11;
  int h = row & 2047;
  const float* W  = agent ? W21 : W11;
  const float* in = agent ? I2  : I1;   // row 0 only
  const float* bv = agent ? b21 : b11;
  float acc = 0.f;
  #pragma unroll
  for (int k = 0; k < 8; ++k)
    acc += W[(size_t)h*DIN + k*64 + lane] * in[k*64 + lane];
  #pragma unroll
  for (int off = 32; off; off >>= 1) acc += __shfl_xor(acc, off);
  if (lane == 0) base[agent*HIDD + h] = acc + bv[h];
}

// ---------------- prep: bf16 out-head weights (rows 0..511) ----------------
__global__ void __launch_bounds__(256) cvt_kernel(
    const float* __restrict__ W12, const float* __restrict__ W22,
    u16* __restrict__ o1, u16* __restrict__ o2)
{
  size_t i = ((size_t)blockIdx.x*256 + threadIdx.x)*4;   // < 512*2048
  float4 a = *reinterpret_cast<const float4*>(W12 + i);
  float4 b = *reinterpret_cast<const float4*>(W22 + i);
  ushort4 ua = { f2bf(a.x), f2bf(a.y), f2bf(a.z), f2bf(a.w) };
  ushort4 ub = { f2bf(b.x), f2bf(b.y), f2bf(b.z), f2bf(b.w) };
  *reinterpret_cast<ushort4*>(o1 + i) = ua;
  *reinterpret_cast<ushort4*>(o2 + i) = ub;
}

// ---------------- agent-split pipelined recurrence ----------------
// WGs 0..15: agent1 (rows g*128..), WGs 16..31: agent2.
// Per step: A1 publishes L1 partial logits -> A2 consumes (softmax com1,
// v+=Wa2@com1, h2, publish L2) -> A1 consumes (softmax com2, w+=Wa1@com2, h1b).
// Sync is one-way per-producer release flags; no RMW atomics, no barrier.
// Overwrite safety: A1 rewrites P1 at step t only after observing all
// F2>=t (A2 set F2=t only after reading P1(t-1)); symmetric for P2.
__global__ void __launch_bounds__(512, 1) team_kernel(
    const float* __restrict__ W11, const float* __restrict__ W21,
    const float* __restrict__ W12, const float* __restrict__ W22,
    const float* __restrict__ b12, const float* __restrict__ b22,
    const float* __restrict__ base,
    float* __restrict__ P1, float* __restrict__ P2,
    u32* __restrict__ F1, u32* __restrict__ F2,
    void* __restrict__ hist1, void* __restrict__ hist2, int hf32)
{
  __shared__ float sWa[HSA][129];   // W1[:,512:] slice  [h][c]
  __shared__ float sU[COMD][129];   // W2[512:,:] slice  [o][h]
  __shared__ float s_b[HSA], s_st[HSA], s_h[HSA];
  __shared__ float s_bc[COMD], s_com[COMD];
  __shared__ float s_lp[512];

  const int wg = blockIdx.x;
  const bool isA1 = (wg < NA);
  const int g = isA1 ? wg : wg - NA;
  const int h0 = g * HSA;
  const int tid = threadIdx.x;

  const float* W1  = isA1 ? W11 : W21;
  const float* W2  = isA1 ? W12 : W22;
  const float* bL2 = isA1 ? b12 : b22;
  const float* bs  = base + (isA1 ? 0 : HIDD);
  float* Pout = isA1 ? P1 : P2;
  float* Pin  = isA1 ? P2 : P1;
  u32*   Fout = isA1 ? F1 : F2;
  u32*   Fin  = isA1 ? F2 : F1;
  void*  hist = isA1 ? hist1 : hist2;
  float* histf = (float*)hist; u16* histu = (u16*)hist;

  for (int idx = tid; idx < HSA*COMD; idx += 512) {
    int h = idx >> 7, c = idx & 127;
    sWa[h][c] = W1[(size_t)(h0+h)*DIN + INPD + c];
  }
  for (int idx = tid; idx < COMD*HSA; idx += 512) {
    int o = idx >> 7, h = idx & 127;
    sU[o][h] = W2[(size_t)(OUTD+o)*HIDD + h0 + h];
  }
  if (tid < COMD) s_bc[tid] = bL2[OUTD + tid];
  if (tid < HSA) { s_b[tid] = bs[h0 + tid]; s_st[tid] = 0.f; }
  __syncthreads();

  for (int t = 0; t < T_STEPS; ++t) {
    const float invd = 1.f / (float)(t+1);

    if (isA1) {
      // ---- produce L1(t): h1a = lrelu(b1 + w/denom), publish U1@h1a ----
      if (tid < HSA) s_h[tid] = lrelu(s_b[tid] + s_st[tid]*invd);
      __syncthreads();
      { int o = tid & 127, r = tid >> 7;
        const float* hp = &s_h[r*32];
        float acc = 0.f;
        #pragma unroll
        for (int j = 0; j < 32; ++j) acc += sU[o][r*32+j] * hp[j];
        s_lp[tid] = acc; }
      __syncthreads();
      if (tid < COMD) {
        float p = s_lp[tid]+s_lp[128+tid]+s_lp[256+tid]+s_lp[384+tid];
        __hip_atomic_store(&Pout[g*COMD+tid], p, __ATOMIC_RELAXED, __HIP_MEMORY_SCOPE_AGENT);
      }
      __syncthreads();
      if (tid == 0)
        __hip_atomic_store(&Fout[g*16], (u32)(t+1), __ATOMIC_RELEASE, __HIP_MEMORY_SCOPE_AGENT);
    }

    // ---- consume phase (A2 consumes L1; A1 consumes L2) ----
    if (tid < NA) {
      while (__hip_atomic_load(&Fin[tid*16], __ATOMIC_ACQUIRE, __HIP_MEMORY_SCOPE_AGENT) < (u32)(t+1)) {}
    }
    __syncthreads();
    { int o = tid & 127, p4 = tid >> 7;
      float s = 0.f;
      #pragma unroll
      for (int j = 0; j < 4; ++j)
        s += __hip_atomic_load(&Pin[(p4*4+j)*COMD + o], __ATOMIC_RELAXED, __HIP_MEMORY_SCOPE_AGENT);
      s_lp[tid] = s; }
    __syncthreads();
    // softmax of 128 logits in wave 0 only (shuffle reductions, no extra barriers)
    if (tid < 64) {
      int o0 = tid, o1 = tid + 64;
      float z0 = SCALE_F * lrelu(s_lp[o0]+s_lp[128+o0]+s_lp[256+o0]+s_lp[384+o0] + s_bc[o0]);
      float z1 = SCALE_F * lrelu(s_lp[o1]+s_lp[128+o1]+s_lp[256+o1]+s_lp[384+o1] + s_bc[o1]);
      float m = fmaxf(z0, z1);
      #pragma unroll
      for (int off = 32; off; off >>= 1) m = fmaxf(m, __shfl_xor(m, off));
      float e0 = __expf(z0 - m), e1 = __expf(z1 - m);
      float s = e0 + e1;
      #pragma unroll
      for (int off = 32; off; off >>= 1) s += __shfl_xor(s, off);
      float r = 1.f / s;
      s_com[o0] = e0 * r; s_com[o1] = e1 * r;
    }
    __syncthreads();
    // state += Wa @ com
    { int h = tid & 127, q = tid >> 7;
      const float* cp = &s_com[q*32];
      float acc = 0.f;
      #pragma unroll
      for (int j = 0; j < 32; ++j) acc += sWa[h][q*32+j] * cp[j];
      s_lp[tid] = acc; }
    __syncthreads();
    if (tid < HSA) {
      float st = s_st[tid] + s_lp[tid]+s_lp[128+tid]+s_lp[256+tid]+s_lp[384+tid];
      s_st[tid] = st;
      float x = lrelu(s_b[tid] + st*invd);
      s_h[tid] = x;   // A2 needs it for L2 logits; A1 write harmless
      if (hf32) histf[(size_t)t*HIDD + h0 + tid] = x;
      else      histu[(size_t)t*HIDD + h0 + tid] = f2bf(x);
    }

    if (!isA1) {
      // ---- produce L2(t): publish U2@h2 ----
      __syncthreads();
      { int o = tid & 127, r = tid >> 7;
        const float* hp = &s_h[r*32];
        float acc = 0.f;
        #pragma unroll
        for (int j = 0; j < 32; ++j) acc += sU[o][r*32+j] * hp[j];
        s_lp[tid] = acc; }
      __syncthreads();
      if (tid < COMD) {
        float p = s_lp[tid]+s_lp[128+tid]+s_lp[256+tid]+s_lp[384+tid];
        __hip_atomic_store(&Pout[g*COMD+tid], p, __ATOMIC_RELAXED, __HIP_MEMORY_SCOPE_AGENT);
      }
      __syncthreads();
      if (tid == 0)
        __hip_atomic_store(&Fout[g*16], (u32)(t+1), __ATOMIC_RELEASE, __HIP_MEMORY_SCOPE_AGENT);
    }
  }
}

// ---------------- dense out-heads from hidden history (t-blocked x8) ----------------
__global__ void __launch_bounds__(256) out_kernel(
    const void* __restrict__ hist1, const void* __restrict__ hist2,
    const u16* __restrict__ Wb1, const u16* __restrict__ Wb2,
    const float* __restrict__ b12, const float* __restrict__ b22,
    float* __restrict__ out, int hf32)
{
  __shared__ float hl[8][2048];
  const int head = blockIdx.x & 1;
  const int t0 = (blockIdx.x >> 1) * 8;
  const int tid = threadIdx.x;
  const void* hist = head ? hist2 : hist1;
  const u16* W = head ? Wb2 : Wb1;
  const float* bias = head ? b22 : b12;
  float* op = out + (size_t)head * T_STEPS * OUTD;

  if (hf32) {
    const float* hf = (const float*)hist;
    for (int idx = tid; idx < 8*2048; idx += 256)
      hl[idx>>11][idx&2047] = hf[(size_t)t0*HIDD + idx];
  } else {
    const u16* hu = (const u16*)hist;
    for (int idx = tid; idx < 8*2048; idx += 256)
      hl[idx>>11][idx&2047] = bf2f(hu[(size_t)t0*HIDD + idx]);
  }
  __syncthreads();

  const int wave = tid >> 6, lane = tid & 63;
  for (int row = wave; row < OUTD; row += 4) {
    const u16* wr = W + (size_t)row*HIDD;
    float acc[8] = {0,0,0,0,0,0,0,0};
    #pragma unroll
    for (int k = 0; k < 8; ++k) {
      const int e = k*256 + lane*4;
      uint2 pw = *reinterpret_cast<const uint2*>(wr + e);
      float w0 = bf2f((u16)(pw.x & 0xffffu));
      float w1 = bf2f((u16)(pw.x >> 16));
      float w2 = bf2f((u16)(pw.y & 0xffffu));
      float w3 = bf2f((u16)(pw.y >> 16));
      #pragma unroll
      for (int tt = 0; tt < 8; ++tt) {
        const float4 hv = *reinterpret_cast<const float4*>(&hl[tt][e]);
        acc[tt] += w0*hv.x + w1*hv.y + w2*hv.z + w3*hv.w;
      }
    }
    #pragma unroll
    for (int tt = 0; tt < 8; ++tt) {
      float a = acc[tt];
      #pragma unroll
      for (int off = 32; off; off >>= 1) a += __shfl_xor(a, off);
      acc[tt] = a;
    }
    if (lane == 0) {
      const float b = bias[row];
      #pragma unroll
      for (int tt = 0; tt < 8; ++tt)
        op[(size_t)(t0+tt)*OUTD + row] = lrelu(acc[tt] + b);
    }
  }
}

extern "C" void kernel_launch(void* const* d_in, const int* in_sizes, int n_in,
                              void* d_out, int out_size, void* d_ws, size_t ws_size,
                              hipStream_t stream)
{
  const float* I1  = (const float*)d_in[0];
  const float* I2  = (const float*)d_in[1];
  const float* W11 = (const float*)d_in[2];
  const float* b11 = (const float*)d_in[3];
  const float* W12 = (const float*)d_in[4];
  const float* b12 = (const float*)d_in[5];
  const float* W21 = (const float*)d_in[6];
  const float* b21 = (const float*)d_in[7];
  const float* W22 = (const float*)d_in[8];
  const float* b22 = (const float*)d_in[9];

  char* ws = (char*)d_ws;
  float* base = (float*)ws;                 // 2*2048 f32
  float* P1 = (float*)(ws + 16384);         // 16*128 f32
  float* P2 = (float*)(ws + 32768);
  u32* F1 = (u32*)(ws + 49152);             // 16 flags, stride 64B
  u32* F2 = (u32*)(ws + 53248);
  char* hist1 = ws + 65536;
  const size_t histF = (size_t)T_STEPS*HIDD*4;
  const size_t histU = (size_t)T_STEPS*HIDD*2;
  const size_t wbB   = (size_t)OUTD*HIDD*2;
  const size_t needF = 65536 + 2*histF + 2*wbB;
  int hf32 = (ws_size >= needF) ? 1 : 0;
  const size_t hb = hf32 ? histF : histU;
  char* hist2 = hist1 + hb;
  u16* Wb1 = (u16*)(hist2 + hb);
  u16* Wb2 = Wb1 + (size_t)OUTD*HIDD;

  hipMemsetAsync(ws + 49152, 0, 8192, stream);
  prep_base_kernel<<<1024, 256, 0, stream>>>(I1, I2, W11, b11, W21, b21, base);
  cvt_kernel<<<1024, 256, 0, stream>>>(W12, W22, Wb1, Wb2);

  void* h1v = (void*)hist1; void* h2v = (void*)hist2;
  void* kargs[] = { (void*)&W11, (void*)&W21, (void*)&W12, (void*)&W22,
                    (void*)&b12, (void*)&b22, (void*)&base,
                    (void*)&P1, (void*)&P2, (void*)&F1, (void*)&F2,
                    (void*)&h1v, (void*)&h2v, (void*)&hf32 };
  hipLaunchCooperativeKernel((const void*)team_kernel, dim3(2*NA), dim3(512),
                             kargs, 0, stream);

  out_kernel<<<(T_STEPS/8)*2, 256, 0, stream>>>(h1v, h2v, Wb1, Wb2, b12, b22,
                                                (float*)d_out, hf32);
}